// Round 7
// baseline (3123.969 us; speedup 1.0000x reference)
//
#include <hip/hip_runtime.h>
#include <hip/hip_bf16.h>
#include <math.h>

#define GN 10000
#define GNP 10112        // GN padded to 128
#define GE 160000
#define GT 4
#define GL 3

typedef __attribute__((ext_vector_type(8))) short short8;
typedef __attribute__((ext_vector_type(4))) float f32x4;
typedef unsigned short u16;

__device__ __forceinline__ u16 f2b(float f) {
  unsigned u = __float_as_uint(f);
  unsigned r = (u + 0x7FFFu + ((u >> 16) & 1u)) >> 16;
  return (u16)r;
}
__device__ __forceinline__ float b2f(u16 b) {
  return __uint_as_float(((unsigned)b) << 16);
}

// async global->LDS, 16B per lane; lds dest must be wave-uniform base
__device__ __forceinline__ void gl_lds16(const void* g, void* l) {
  __builtin_amdgcn_global_load_lds(
      (const __attribute__((address_space(1))) void*)g,
      (__attribute__((address_space(3))) void*)l, 16, 0, 0);
}

// ---------------------------------------------------------------------------
// fp32 tiled GEMM (only the tiny 32x32 post-W2 uses this)
// ---------------------------------------------------------------------------
template<bool RELU_C, bool GATHER, bool OUTB>
__global__ __launch_bounds__(256) void gemm_k(
    const float* __restrict__ A, const int* __restrict__ idx,
    const float* __restrict__ B, const float* __restrict__ bias,
    void* __restrict__ Cv,
    int M, int N, int K, int lda, int ldb, int ldc)
{
  __shared__ float As[16][65];
  __shared__ float Bs[16][65];
  const int tid = threadIdx.x;
  const int brow = blockIdx.y * 64, bcol = blockIdx.x * 64;
  const int tr = ((tid >> 4) & 15) << 2;
  const int tc = (tid & 15) << 2;
  float acc[4][4] = {{0.f}};

  for (int k0 = 0; k0 < K; k0 += 16) {
    for (int i = tid; i < 64 * 16; i += 256) {
      int r = i >> 4, c = i & 15;
      int gr = brow + r, gk = k0 + c;
      float v = 0.f;
      if (gr < M && gk < K) {
        size_t ar = GATHER ? (size_t)idx[gr] : (size_t)gr;
        v = A[ar * (size_t)lda + gk];
      }
      As[c][r] = v;
    }
    for (int i = tid; i < 16 * 64; i += 256) {
      int r = i >> 6, c = i & 63;
      int gk = k0 + r, gc = bcol + c;
      Bs[r][c] = (gk < K && gc < N) ? B[(size_t)gk * ldb + gc] : 0.f;
    }
    __syncthreads();
#pragma unroll
    for (int kk = 0; kk < 16; ++kk) {
      float a[4], b[4];
#pragma unroll
      for (int i = 0; i < 4; ++i) a[i] = As[kk][tr + i];
#pragma unroll
      for (int j = 0; j < 4; ++j) b[j] = Bs[kk][tc + j];
#pragma unroll
      for (int i = 0; i < 4; ++i)
#pragma unroll
        for (int j = 0; j < 4; ++j) acc[i][j] += a[i] * b[j];
    }
    __syncthreads();
  }

#pragma unroll
  for (int i = 0; i < 4; ++i) {
    int gr = brow + tr + i;
    if (gr >= M) continue;
#pragma unroll
    for (int j = 0; j < 4; ++j) {
      int gc = bcol + tc + j;
      if (gc >= N) continue;
      float v = acc[i][j] + bias[gc];
      if (RELU_C) v = fmaxf(v, 0.f);
      if (OUTB) ((u16*)Cv)[(size_t)gr * ldc + gc] = f2b(v);
      else      ((float*)Cv)[(size_t)gr * ldc + gc] = v;
    }
  }
}

// ---------------------------------------------------------------------------
// bf16 MFMA GEMM, 64x64 tile (kept for N=64 outputs: postW1 / med / eu2)
// ---------------------------------------------------------------------------
template<bool RELU, bool GATHER, bool MUL, bool OUTB>
__global__ __launch_bounds__(256) void mgemm_k(
    const u16* __restrict__ A, const u16* __restrict__ A2,
    const int* __restrict__ idx,
    const u16* __restrict__ Bt, const float* __restrict__ bias,
    void* __restrict__ Cv,
    int M, int N, int K, int lda, int ldc)
{
  __shared__ u16 As[64 * 64];
  __shared__ u16 Bs[64 * 64];
  __shared__ int ridx[64];
  const int tid = threadIdx.x;
  const int brow = blockIdx.y * 64, bcol = blockIdx.x * 64;
  const int wid = tid >> 6, lane = tid & 63;
  const int wr = wid >> 1, wc = wid & 1;
  const int lrow = lane & 15, lk8 = (lane >> 4) * 8;

  if (tid < 64) ridx[tid] = GATHER ? idx[brow + tid] : (brow + tid);
  __syncthreads();

  f32x4 acc[2][2] = {};

  for (int k0 = 0; k0 < K; k0 += 64) {
#pragma unroll
    for (int s = 0; s < 2; ++s) {
      int c = tid + s * 256;
      int r = c >> 3, kq = (c & 7) * 8;
      const u16* sp = A + (size_t)ridx[r] * lda + k0 + kq;
      short8 v = *(const short8*)sp;
      if (MUL) {
        const u16* sp2 = A2 + (size_t)ridx[r] * lda + k0 + kq;
        short8 v2 = *(const short8*)sp2;
#pragma unroll
        for (int e = 0; e < 8; ++e)
          v[e] = (short)f2b(b2f((u16)v[e]) * b2f((u16)v2[e]));
      }
      int byt = (r * 128 + kq * 2) ^ ((r & 7) << 4);
      *(short8*)((char*)As + byt) = v;
    }
#pragma unroll
    for (int s = 0; s < 2; ++s) {
      int c = tid + s * 256;
      int r = c >> 3, kq = (c & 7) * 8;
      const u16* sp = Bt + (size_t)(bcol + r) * K + k0 + kq;
      short8 v = *(const short8*)sp;
      int byt = (r * 128 + kq * 2) ^ ((r & 7) << 4);
      *(short8*)((char*)Bs + byt) = v;
    }
    __syncthreads();
#pragma unroll
    for (int ks = 0; ks < 2; ++ks) {
      short8 a[2], b[2];
#pragma unroll
      for (int m = 0; m < 2; ++m) {
        int r = wr * 32 + m * 16 + lrow;
        int kk = ks * 32 + lk8;
        int byt = (r * 128 + kk * 2) ^ ((r & 7) << 4);
        a[m] = *(const short8*)((const char*)As + byt);
      }
#pragma unroll
      for (int n = 0; n < 2; ++n) {
        int r = wc * 32 + n * 16 + lrow;
        int kk = ks * 32 + lk8;
        int byt = (r * 128 + kk * 2) ^ ((r & 7) << 4);
        b[n] = *(const short8*)((const char*)Bs + byt);
      }
#pragma unroll
      for (int m = 0; m < 2; ++m)
#pragma unroll
        for (int n = 0; n < 2; ++n)
          acc[m][n] = __builtin_amdgcn_mfma_f32_16x16x32_bf16(a[m], b[n], acc[m][n], 0, 0, 0);
    }
    __syncthreads();
  }

#pragma unroll
  for (int m = 0; m < 2; ++m)
#pragma unroll
    for (int n = 0; n < 2; ++n) {
      int col = bcol + wc * 32 + n * 16 + (lane & 15);
      float bv = bias[col];
#pragma unroll
      for (int j = 0; j < 4; ++j) {
        int row = brow + wr * 32 + m * 16 + (lane >> 4) * 4 + j;
        float v = acc[m][n][j] + bv;
        if (RELU) v = fmaxf(v, 0.f);
        if (OUTB) ((u16*)Cv)[(size_t)row * ldc + col] = f2b(v);
        else      ((float*)Cv)[(size_t)row * ldc + col] = v;
      }
    }
}

// ---------------------------------------------------------------------------
// bf16 MFMA GEMM, 128x128 tile, BK=64, 4 waves (2x2), 4x4 frags/wave.
// Non-MUL: async global_load_lds staging — LDS dest LINEAR (lane order),
// XOR swizzle applied to the GLOBAL source granule (g ^= r&7), reads use
// the same XOR (involution). MUL: reg-staged swizzled stores (old path).
// M%128==0, N%128==0, K%64==0.
// ---------------------------------------------------------------------------
template<bool RELU, bool GATHER, bool MUL, bool OUTB>
__global__ __launch_bounds__(256) void mg2_k(
    const u16* __restrict__ A, const u16* __restrict__ A2,
    const int* __restrict__ idx,
    const u16* __restrict__ Bt, const float* __restrict__ bias,
    void* __restrict__ Cv,
    int M, int N, int K, int lda, int ldc)
{
  __shared__ u16 As[128 * 64];
  __shared__ u16 Bs[128 * 64];
  __shared__ int ridx[128];
  const int tid = threadIdx.x;
  const int brow = blockIdx.y * 128, bcol = blockIdx.x * 128;
  const int wid = tid >> 6, lane = tid & 63;
  const int wr = wid >> 1, wc = wid & 1;          // 2x2 waves, 64x64 each
  const int lrow = lane & 15, lkg = lane >> 4;    // lkg 0..3

  if (GATHER) {
    if (tid < 128) ridx[tid] = idx[brow + tid];
    __syncthreads();
  }

  f32x4 acc[4][4] = {};

  // per-thread source pointers (swizzled granule), constant across k-loop
  const char* srcA[4];
  const char* srcB[4];
#pragma unroll
  for (int s = 0; s < 4; ++s) {
    int i = tid + s * 256;
    int r = i >> 3, g = i & 7;
    size_t grow = GATHER ? (size_t)ridx[r] : (size_t)(brow + r);
    int gq = (g ^ (r & 7)) * 8;
    srcA[s] = (const char*)(A + grow * lda + gq);
    srcB[s] = (const char*)(Bt + (size_t)(bcol + r) * K + gq);
  }

  for (int k0 = 0; k0 < K; k0 += 64) {
    if constexpr (!MUL) {
      // async: lds dest = linear lane order (s*4096 + wid*1024 + lane*16)
#pragma unroll
      for (int s = 0; s < 4; ++s)
        gl_lds16(srcA[s] + (size_t)k0 * 2, (char*)As + s * 4096 + wid * 1024);
#pragma unroll
      for (int s = 0; s < 4; ++s)
        gl_lds16(srcB[s] + (size_t)k0 * 2, (char*)Bs + s * 4096 + wid * 1024);
    } else {
      // reg-staged with swizzled LDS store (A .* A2)
#pragma unroll
      for (int s = 0; s < 4; ++s) {
        int i = tid + s * 256;
        int r = i >> 3, kq = (i & 7) * 8;
        size_t grow = GATHER ? (size_t)ridx[r] : (size_t)(brow + r);
        const u16* sp = A + grow * lda + k0 + kq;
        short8 v = *(const short8*)sp;
        const u16* sp2 = A2 + grow * lda + k0 + kq;
        short8 v2 = *(const short8*)sp2;
#pragma unroll
        for (int e = 0; e < 8; ++e)
          v[e] = (short)f2b(b2f((u16)v[e]) * b2f((u16)v2[e]));
        int byt = (r * 128 + kq * 2) ^ ((r & 7) << 4);
        *(short8*)((char*)As + byt) = v;
      }
#pragma unroll
      for (int s = 0; s < 4; ++s) {
        int i = tid + s * 256;
        int r = i >> 3, kq = (i & 7) * 8;
        const u16* sp = Bt + (size_t)(bcol + r) * K + k0 + kq;
        short8 v = *(const short8*)sp;
        int byt = (r * 128 + kq * 2) ^ ((r & 7) << 4);
        *(short8*)((char*)Bs + byt) = v;
      }
    }
    __syncthreads();
#pragma unroll
    for (int ks = 0; ks < 2; ++ks) {
      const int kb = ks * 64 + lkg * 16;          // byte offset of lane's 16B in k
      short8 a[4], b[4];
#pragma unroll
      for (int m = 0; m < 4; ++m) {
        int r = wr * 64 + m * 16 + lrow;
        int byt = (r * 128 + kb) ^ ((r & 7) << 4);
        a[m] = *(const short8*)((const char*)As + byt);
      }
#pragma unroll
      for (int n = 0; n < 4; ++n) {
        int r = wc * 64 + n * 16 + lrow;
        int byt = (r * 128 + kb) ^ ((r & 7) << 4);
        b[n] = *(const short8*)((const char*)Bs + byt);
      }
#pragma unroll
      for (int m = 0; m < 4; ++m)
#pragma unroll
        for (int n = 0; n < 4; ++n)
          acc[m][n] = __builtin_amdgcn_mfma_f32_16x16x32_bf16(a[m], b[n], acc[m][n], 0, 0, 0);
    }
    __syncthreads();
  }

#pragma unroll
  for (int m = 0; m < 4; ++m)
#pragma unroll
    for (int n = 0; n < 4; ++n) {
      int col = bcol + wc * 64 + n * 16 + lrow;
      float bv = bias[col];
#pragma unroll
      for (int j = 0; j < 4; ++j) {
        int row = brow + wr * 64 + m * 16 + lkg * 4 + j;
        float v = acc[m][n][j] + bv;
        if (RELU) v = fmaxf(v, 0.f);
        if (OUTB) ((u16*)Cv)[(size_t)row * ldc + col] = f2b(v);
        else      ((float*)Cv)[(size_t)row * ldc + col] = v;
      }
    }
}

// ---------------------------------------------------------------------------
// Edge sort by dst (counting sort)
// ---------------------------------------------------------------------------
__global__ void deg_kernel(const int* __restrict__ dst, int* __restrict__ deg, int E)
{
  int e = blockIdx.x * blockDim.x + threadIdx.x;
  if (e < E) atomicAdd(&deg[dst[e]], 1);
}

__global__ void scan_kernel(const int* __restrict__ deg, int* __restrict__ rowptr, int n)
{
  __shared__ int tmp[256];
  __shared__ int carry;
  if (threadIdx.x == 0) carry = 0;
  __syncthreads();
  for (int base = 0; base < n; base += 256) {
    int i = base + (int)threadIdx.x;
    int v = (i < n) ? deg[i] : 0;
    tmp[threadIdx.x] = v;
    __syncthreads();
    for (int off = 1; off < 256; off <<= 1) {
      int t = (threadIdx.x >= (unsigned)off) ? tmp[threadIdx.x - off] : 0;
      __syncthreads();
      tmp[threadIdx.x] += t;
      __syncthreads();
    }
    if (i < n) rowptr[i] = carry + tmp[threadIdx.x] - v;
    __syncthreads();
    if (threadIdx.x == 0) carry += tmp[255];
    __syncthreads();
  }
  if (threadIdx.x == 0) rowptr[n] = carry;
}

__global__ void scatter_kernel(const int* __restrict__ dst, int* __restrict__ cursor,
                               int* __restrict__ eidx, int E)
{
  int e = blockIdx.x * blockDim.x + threadIdx.x;
  if (e < E) {
    int p = atomicAdd(&cursor[dst[e]], 1);
    eidx[p] = e;
  }
}

// ---------------------------------------------------------------------------
// Batched weight transpose+convert: W[b] (K x N fp32) -> Wt[b] (N x K bf16)
// ---------------------------------------------------------------------------
__global__ void wtb_kernel(const float* __restrict__ W, u16* __restrict__ Wt,
                           int K, int N, size_t wtStride)
{
  int b = blockIdx.y;
  const float* Wb = W + (size_t)b * K * N;
  u16* Wtb = Wt + (size_t)b * wtStride;
  for (int i = blockIdx.x * blockDim.x + threadIdx.x; i < K * N;
       i += gridDim.x * blockDim.x) {
    int k = i / N, n = i % N;
    Wtb[(size_t)n * K + k] = f2b(Wb[i]);
  }
}

__global__ void biaspad_kernel(const float* __restrict__ b32, float* __restrict__ b64, int total)
{
  int i = blockIdx.x * blockDim.x + threadIdx.x;
  if (i >= total) return;
  b64[(i / 32) * 64 + (i % 32)] = b32[i];
}

__global__ void f2b_kernel(const float* __restrict__ in, u16* __restrict__ out, int n)
{
  int i = blockIdx.x * blockDim.x + threadIdx.x;
  if (i < n) out[i] = f2b(in[i]);
}

// ---------------------------------------------------------------------------
// Build Acat (bf16) cols 0..255 for a chunk (sorted order): [xb[dst] | xb[src]]
// ---------------------------------------------------------------------------
__global__ void build_acat_kernel(const u16* __restrict__ xb,
                                  const int* __restrict__ eidx,
                                  const int* __restrict__ srcA,
                                  const int* __restrict__ dstA,
                                  long base, int Mc, u16* __restrict__ Acat)
{
  int i = blockIdx.x * blockDim.x + threadIdx.x;
  int total = Mc * 32;
  if (i >= total) return;
  int p = i >> 5, q = i & 31;
  int e = eidx[base + p];
  int c0 = q * 8;
  const u16* sp = (c0 < 128) ? (xb + (size_t)dstA[e] * 128 + c0)
                             : (xb + (size_t)srcA[e] * 128 + (c0 - 128));
  *(int4*)(Acat + (size_t)p * 384 + c0) = *(const int4*)sp;
}

// ---------------------------------------------------------------------------
// Aggregator init
// ---------------------------------------------------------------------------
__global__ void agg_init_kernel(float* __restrict__ s, float* __restrict__ ss,
                                unsigned* __restrict__ mx, int total)
{
  int i = blockIdx.x * blockDim.x + threadIdx.x;
  if (i >= total) return;
  s[i] = 0.f; ss[i] = 0.f; mx[i] = 0x007FFFFFu;
}

// ---------------------------------------------------------------------------
// Sorted-segment merge (bf16 msg, all 4 towers via blockIdx.y)
// ---------------------------------------------------------------------------
__global__ __launch_bounds__(128) void agg_merge_kernel(
    const u16* __restrict__ msgb, size_t msgStride,
    const int* __restrict__ eidx, const int* __restrict__ dst, long base,
    float* __restrict__ sumb, float* __restrict__ sumsqb,
    unsigned* __restrict__ mxb, int Nn)
{
  __shared__ int nid[64];
  const int t = blockIdx.y;
  const u16* msg = msgb + (size_t)t * msgStride;
  float* sb = sumb + (size_t)t * Nn * 128;
  float* qb = sumsqb + (size_t)t * Nn * 128;
  unsigned* xb_ = mxb + (size_t)t * Nn * 128;
  const int tid = threadIdx.x;
  const long p0 = (long)blockIdx.x * 64;
  if (tid < 64) nid[tid] = dst[eidx[base + p0 + tid]];
  __syncthreads();
  int col = tid;
  int cur = nid[0];
  float s = 0.f, ssq = 0.f, m = -INFINITY;
  for (int rr = 0; rr < 64; ++rr) {
    int n = nid[rr];
    if (n != cur) {
      size_t o = (size_t)cur * 128 + col;
      atomicAdd(&sb[o], s);
      atomicAdd(&qb[o], ssq);
      unsigned ub = __float_as_uint(m);
      atomicMax(&xb_[o], (ub & 0x80000000u) ? ~ub : (ub | 0x80000000u));
      cur = n; s = 0.f; ssq = 0.f; m = -INFINITY;
    }
    float v = b2f(msg[(size_t)(p0 + rr) * 128 + col]);
    s += v; ssq += v * v; m = fmaxf(m, v);
  }
  size_t o = (size_t)cur * 128 + col;
  atomicAdd(&sb[o], s);
  atomicAdd(&qb[o], ssq);
  unsigned ub = __float_as_uint(m);
  atomicMax(&xb_[o], (ub & 0x80000000u) ? ~ub : (ub | 0x80000000u));
}

// ---------------------------------------------------------------------------
// Finalize (per tower): write bf16 cat tile [x | mean | max | std] (N x 512)
// ---------------------------------------------------------------------------
__global__ void finalize_kernel(
    const float* __restrict__ sumb, const float* __restrict__ sumsqb,
    const unsigned* __restrict__ mxb, const int* __restrict__ rowptr,
    const float* __restrict__ x, u16* __restrict__ catb, int total)
{
  int i = blockIdx.x * blockDim.x + threadIdx.x;
  if (i >= total) return;               // total = N*128
  int n = i >> 7, c = i & 127;
  float cnt = fmaxf((float)(rowptr[n + 1] - rowptr[n]), 1.f);
  float mean = sumb[i] / cnt;
  float msq  = sumsqb[i] / cnt;
  float sd = sqrtf(fmaxf(msq - mean * mean, 0.f) + 1e-5f);
  unsigned u = mxb[i];
  unsigned bits = (u & 0x80000000u) ? (u & 0x7FFFFFFFu) : ~u;
  float mxv = __uint_as_float(bits);
  if ((bits & 0x7F800000u) == 0x7F800000u) mxv = 0.f;
  u16* cb = catb + (size_t)n * 512;
  cb[c]       = f2b(x[(size_t)n * 128 + c]);
  cb[128 + c] = f2b(mean);
  cb[256 + c] = f2b(mxv);
  cb[384 + c] = f2b(sd);
}

// ---------------------------------------------------------------------------
// GRU elementwise combine
// ---------------------------------------------------------------------------
__global__ void gru_kernel(const float* __restrict__ gi, const float* __restrict__ gh,
                           const float* __restrict__ h, float* __restrict__ hout, int total)
{
  int i = blockIdx.x * blockDim.x + threadIdx.x;
  if (i >= total) return;
  int n = i >> 7, c = i & 127;
  const float* gin = gi + (size_t)n * 384;
  const float* ghn = gh + (size_t)n * 384;
  float ir = gin[c], iz = gin[128 + c], inn = gin[256 + c];
  float hr = ghn[c], hz = ghn[128 + c], hn = ghn[256 + c];
  float r = 1.f / (1.f + __expf(-(ir + hr)));
  float z = 1.f / (1.f + __expf(-(iz + hz)));
  float nn = tanhf(inn + r * hn);
  hout[i] = (1.f - z) * nn + z * h[i];
}

// ---------------------------------------------------------------------------
// ecat = [med bf16 (M,64) | bf16(ea fp32) (M,64)] -> out bf16 (M,128)
// ---------------------------------------------------------------------------
__global__ void concat_b_kernel(const u16* __restrict__ med, const float* __restrict__ ea,
                                u16* __restrict__ out, long total)
{
  long i = (long)blockIdx.x * blockDim.x + threadIdx.x;
  if (i >= total) return;
  long e = i >> 7;
  int c = (int)(i & 127);
  out[i] = (c < 64) ? med[e * 64 + c] : f2b(ea[e * 64 + (c - 64)]);
}

// ---------------------------------------------------------------------------
extern "C" void kernel_launch(void* const* d_in, const int* in_sizes, int n_in,
                              void* d_out, int out_size, void* d_ws, size_t ws_size,
                              hipStream_t stream)
{
  const int N_ = GN, E_ = GE, Np = GNP;

  const float* x_in   = (const float*)d_in[0];
  const int*   src    = (const int*)d_in[1];
  const int*   dst    = src + E_;
  const float* ea_in  = (const float*)d_in[2];
  const float* enc_W  = (const float*)d_in[3];
  const float* enc_b  = (const float*)d_in[4];
  const float* pre_W1 = (const float*)d_in[5];
  const float* pre_b1 = (const float*)d_in[6];
  const float* pre_W2 = (const float*)d_in[7];
  const float* pre_b2 = (const float*)d_in[8];
  const float* post_W1 = (const float*)d_in[9];
  const float* post_b1 = (const float*)d_in[10];
  const float* post_W2 = (const float*)d_in[11];
  const float* post_b2 = (const float*)d_in[12];
  const float* lin_W  = (const float*)d_in[13];
  const float* lin_b  = (const float*)d_in[14];
  const float* gru_Wi = (const float*)d_in[15];
  const float* gru_Wh = (const float*)d_in[16];
  const float* gru_bi = (const float*)d_in[17];
  const float* gru_bh = (const float*)d_in[18];
  const float* fcu_W1 = (const float*)d_in[19];
  const float* fcu_b1 = (const float*)d_in[20];
  const float* fcu_W2 = (const float*)d_in[21];
  const float* fcu_b2 = (const float*)d_in[22];
  const float* fcv_W1 = (const float*)d_in[23];
  const float* fcv_b1 = (const float*)d_in[24];
  const float* fcv_W2 = (const float*)d_in[25];
  const float* fcv_b2 = (const float*)d_in[26];
  const float* fc_W1  = (const float*)d_in[27];
  const float* fc_b1  = (const float*)d_in[28];
  const float* fc_W2  = (const float*)d_in[29];
  const float* fc_b2  = (const float*)d_in[30];
  const float* eu_W1  = (const float*)d_in[31];
  const float* eu_b1  = (const float*)d_in[32];
  const float* eu_W2  = (const float*)d_in[33];
  const float* eu_b2  = (const float*)d_in[34];

  // ---- workspace arena ----
  size_t used = 0;
  char* w = (char*)d_ws;
  auto alloc = [&](size_t bytes) {
    char* p = w + used;
    used += (bytes + 255) & ~(size_t)255;
    return p;
  };
  float*    sumb   = (float*)alloc((size_t)N_ * 512 * 4);   // [t][n][128]
  float*    sumsqb = (float*)alloc((size_t)N_ * 512 * 4);
  unsigned* mxb    = (unsigned*)alloc((size_t)N_ * 512 * 4);
  float*    q1   = (float*)alloc((size_t)Np * 64 * 4);
  u16*      q2b  = (u16*)alloc((size_t)Np * 128 * 2);
  u16*      mbb  = (u16*)alloc((size_t)Np * 128 * 2);
  float*    gib  = (float*)alloc((size_t)Np * 384 * 4);
  float*    ghb  = (float*)alloc((size_t)Np * 384 * 4);
  float*    Hb   = (float*)alloc((size_t)N_ * 128 * 4);
  u16*      xb   = (u16*)alloc((size_t)Np * 128 * 2);
  u16*      catb = (u16*)alloc((size_t)Np * 512 * 2);
  u16*      eab  = (u16*)alloc((size_t)E_ * 64 * 2);
  // bf16 transposed weights
  u16* encWt  = (u16*)alloc((size_t)GL * 128 * 64 * 2);
  u16* preW1t = (u16*)alloc((size_t)GL * GT * 128 * 384 * 2);
  u16* preW2t = (u16*)alloc((size_t)GL * GT * 128 * 128 * 2);
  u16* postW1t = (u16*)alloc((size_t)GL * GT * 64 * 512 * 2);
  float* postb1p = (float*)alloc((size_t)GL * GT * 64 * 4);
  u16* linWt  = (u16*)alloc((size_t)GL * 128 * 128 * 2);
  u16* gruWit = (u16*)alloc((size_t)384 * 128 * 2);
  u16* gruWht = (u16*)alloc((size_t)384 * 128 * 2);
  u16* fcuW1t = (u16*)alloc((size_t)256 * 128 * 2);
  u16* fcuW2t = (u16*)alloc((size_t)256 * 256 * 2);
  u16* fcvW1t = (u16*)alloc((size_t)256 * 128 * 2);
  u16* fcvW2t = (u16*)alloc((size_t)256 * 256 * 2);
  u16* fcW1t  = (u16*)alloc((size_t)256 * 256 * 2);
  u16* fcW2t  = (u16*)alloc((size_t)64 * 256 * 2);
  u16* euW1t  = (u16*)alloc((size_t)128 * 128 * 2);
  u16* euW2t  = (u16*)alloc((size_t)64 * 128 * 2);
  int* eidx   = (int*)alloc((size_t)E_ * 4);
  int* degb   = (int*)alloc((size_t)(N_ + 1) * 4);
  int* rowptr = (int*)alloc((size_t)(N_ + 1) * 4);
  int* cursor = (int*)alloc((size_t)(N_ + 1) * 4);

  // chunk arena: 2048 B/row. Ec capped so the edge-chain ping-pong buffers
  // (3 x Ec x 512 B) stay L3-resident (~150 MB live set at 98304).
  size_t avail = (ws_size > used + 4096) ? (ws_size - used - 4096) : 0;
  long Ec = (long)(avail / 2048);
  if (Ec > E_) Ec = E_;
  if (Ec > 98304) Ec = 98304;
  Ec &= ~255L;
  if (Ec < 256) return;   // ws too small: fail cleanly
  char* arena = alloc((size_t)Ec * 2048);
  if (used > ws_size) return;
  const int nchunks = (int)((E_ + Ec - 1) / Ec);
  u16*   hball = (u16*)arena;                          // Ec x 512 bf16
  u16*   Acatb = (u16*)(arena + (size_t)Ec * 1024);    // Ec x 384 bf16
  u16*   msgb  = (u16*)(arena + (size_t)Ec * 1024);    // 4 x Ec x 128 bf16
  u16* C1b = (u16*)arena;
  u16* C2b = (u16*)(arena + (size_t)Ec * 512);
  u16* C3b = (u16*)(arena + (size_t)Ec * 1024);

  float* out = (float*)d_out;
  float* EAp = out + (size_t)N_ * 128;   // ea state lives in d_out

  // ---- one-time setup ----
  hipMemsetAsync(degb, 0, (size_t)N_ * 4, stream);
  deg_kernel<<<(E_ + 255) / 256, 256, 0, stream>>>(dst, degb, E_);
  scan_kernel<<<1, 256, 0, stream>>>(degb, rowptr, N_);
  hipMemcpyAsync(cursor, rowptr, (size_t)N_ * 4, hipMemcpyDeviceToDevice, stream);
  scatter_kernel<<<(E_ + 255) / 256, 256, 0, stream>>>(dst, cursor, eidx, E_);

  hipMemsetAsync(postW1t, 0, (size_t)GL * GT * 64 * 512 * 2, stream);
  hipMemsetAsync(postb1p, 0, (size_t)GL * GT * 64 * 4, stream);
  {
    dim3 gb(48, GL);
    wtb_kernel<<<gb, 256, 0, stream>>>(enc_W, encWt, 64, 128, 128 * 64);
    wtb_kernel<<<gb, 256, 0, stream>>>(lin_W, linWt, 128, 128, 128 * 128);
    dim3 gt(48, GL * GT);
    wtb_kernel<<<gt, 256, 0, stream>>>(pre_W1, preW1t, 384, 128, 128 * 384);
    wtb_kernel<<<gt, 256, 0, stream>>>(pre_W2, preW2t, 128, 128, 128 * 128);
    wtb_kernel<<<gt, 256, 0, stream>>>(post_W1, postW1t, 512, 32, 64 * 512);
    dim3 g1(48, 1);
    wtb_kernel<<<g1, 256, 0, stream>>>(gru_Wi, gruWit, 128, 384, 384 * 128);
    wtb_kernel<<<g1, 256, 0, stream>>>(gru_Wh, gruWht, 128, 384, 384 * 128);
    wtb_kernel<<<g1, 256, 0, stream>>>(fcu_W1, fcuW1t, 128, 256, 256 * 128);
    wtb_kernel<<<g1, 256, 0, stream>>>(fcu_W2, fcuW2t, 256, 256, 256 * 256);
    wtb_kernel<<<g1, 256, 0, stream>>>(fcv_W1, fcvW1t, 128, 256, 256 * 128);
    wtb_kernel<<<g1, 256, 0, stream>>>(fcv_W2, fcvW2t, 256, 256, 256 * 256);
    wtb_kernel<<<g1, 256, 0, stream>>>(fc_W1, fcW1t, 256, 256, 256 * 256);
    wtb_kernel<<<g1, 256, 0, stream>>>(fc_W2, fcW2t, 256, 64, 64 * 256);
    wtb_kernel<<<g1, 256, 0, stream>>>(eu_W1, euW1t, 128, 128, 128 * 128);
    wtb_kernel<<<g1, 256, 0, stream>>>(eu_W2, euW2t, 128, 64, 64 * 128);
  }
  biaspad_kernel<<<(GL * GT * 32 + 255) / 256, 256, 0, stream>>>(
      post_b1, postb1p, GL * GT * 32);

  f2b_kernel<<<(N_ * 128 + 255) / 256, 256, 0, stream>>>(x_in, xb, N_ * 128);
  f2b_kernel<<<(E_ * 64 + 255) / 256, 256, 0, stream>>>(ea_in, eab, E_ * 64);

  const float* x_cur = x_in;
  const float* ea_cur = ea_in;

  for (int l = 0; l < GL; ++l) {
    // ---- PNA conv ----
    agg_init_kernel<<<(N_ * 512 + 255) / 256, 256, 0, stream>>>(sumb, sumsqb, mxb, N_ * 512);
    for (int c = 0; c < nchunks; ++c) {
      long p0 = (long)c * Ec;
      int Mc = (int)(((long)E_ - p0 < Ec) ? ((long)E_ - p0) : Ec);
      dim3 gEnc(1, Mc / 128), gH(4, Mc / 128), gMsg(1, Mc / 128);
      // enc chunk (gathered bf16) -> Acat cols 256..383
      mg2_k<false, true, false, true><<<gEnc, 256, 0, stream>>>(
          eab, nullptr, eidx + p0, encWt + (size_t)l * 128 * 64,
          enc_b + (size_t)l * 128, Acatb + 256, Mc, 128, 64, 64, 384);
      build_acat_kernel<<<(Mc * 32 + 255) / 256, 256, 0, stream>>>(
          xb, eidx, src, dst, p0, Mc, Acatb);
      // h (all towers): Mc x 512, K=384
      mg2_k<true, false, false, true><<<gH, 256, 0, stream>>>(
          Acatb, nullptr, nullptr, preW1t + (size_t)l * 512 * 384,
          pre_b1 + (size_t)l * 512, hball, Mc, 512, 384, 384, 512);
      // msg per tower -> msgb[t] (bf16)
      for (int t = 0; t < GT; ++t) {
        mg2_k<false, false, false, true><<<gMsg, 256, 0, stream>>>(
            hball + t * 128, nullptr, nullptr,
            preW2t + ((size_t)l * GT + t) * 128 * 128,
            pre_b2 + (size_t)l * 512 + t * 128,
            msgb + (size_t)t * Ec * 128, Mc, 128, 128, 512, 128);
      }
      // merge all towers
      dim3 gMg(Mc / 64, GT);
      agg_merge_kernel<<<gMg, 128, 0, stream>>>(
          msgb, (size_t)Ec * 128, eidx, dst, p0, sumb, sumsqb, mxb, N_);
    }
    for (int t = 0; t < GT; ++t) {
      finalize_kernel<<<(N_ * 128 + 255) / 256, 256, 0, stream>>>(
          sumb + (size_t)t * N_ * 128, sumsqb + (size_t)t * N_ * 128,
          mxb + (size_t)t * N_ * 128, rowptr, x_cur, catb, N_ * 128);
      dim3 gP1(1, Np / 64);
      mgemm_k<true, false, false, false><<<gP1, 256, 0, stream>>>(
          catb, nullptr, nullptr, postW1t + ((size_t)l * GT + t) * 64 * 512,
          postb1p + ((size_t)l * GT + t) * 64, q1, Np, 64, 512, 512, 64);
      dim3 gP2(1, (N_ + 63) / 64);
      gemm_k<false, false, true><<<gP2, 256, 0, stream>>>(
          q1, nullptr, post_W2 + ((size_t)l * GT + t) * 32 * 32,
          post_b2 + ((size_t)l * GT + t) * 32,
          q2b + t * 32, N_, 32, 32, 64, 32, 128);
    }
    {
      dim3 gL(1, Np / 128), gG(3, Np / 128);
      mg2_k<false, false, false, true><<<gL, 256, 0, stream>>>(
          q2b, nullptr, nullptr, linWt + (size_t)l * 128 * 128,
          lin_b + (size_t)l * 128, mbb, Np, 128, 128, 128, 128);
      mg2_k<false, false, false, false><<<gG, 256, 0, stream>>>(
          mbb, nullptr, nullptr, gruWit, gru_bi, gib, Np, 384, 128, 128, 384);
      mg2_k<false, false, false, false><<<gG, 256, 0, stream>>>(
          xb, nullptr, nullptr, gruWht, gru_bh, ghb, Np, 384, 128, 128, 384);
    }
    gru_kernel<<<(N_ * 128 + 255) / 256, 256, 0, stream>>>(gib, ghb, x_cur, Hb, N_ * 128);
    f2b_kernel<<<(N_ * 128 + 255) / 256, 256, 0, stream>>>(Hb, xb, N_ * 128);

    // ---- edge update (chunked, bf16 MFMA chain) ----
    for (int c = 0; c < nchunks; ++c) {
      long e0 = (long)c * Ec;
      int Mc = (int)(((long)E_ - e0 < Ec) ? ((long)E_ - e0) : Ec);
      dim3 g2m(2, Mc / 128), g1m(1, Mc / 128), g64(1, Mc / 64);
      mg2_k<true, true, false, true><<<g2m, 256, 0, stream>>>(
          xb, nullptr, src + e0, fcuW1t, fcu_b1, C1b, Mc, 256, 128, 128, 256);
      mg2_k<true, false, false, true><<<g2m, 256, 0, stream>>>(
          C1b, nullptr, nullptr, fcuW2t, fcu_b2, C2b, Mc, 256, 256, 256, 256);
      mg2_k<true, true, false, true><<<g2m, 256, 0, stream>>>(
          xb, nullptr, dst + e0, fcvW1t, fcv_b1, C1b, Mc, 256, 128, 128, 256);
      mg2_k<true, false, false, true><<<g2m, 256, 0, stream>>>(
          C1b, nullptr, nullptr, fcvW2t, fcv_b2, C3b, Mc, 256, 256, 256, 256);
      mg2_k<true, false, true, true><<<g2m, 256, 0, stream>>>(
          C2b, C3b, nullptr, fcW1t, fc_b1, C1b, Mc, 256, 256, 256, 256);
      mgemm_k<true, false, false, true><<<g64, 256, 0, stream>>>(
          C1b, nullptr, nullptr, fcW2t, fc_b2, C2b, Mc, 64, 256, 256, 64);
      concat_b_kernel<<<(int)(((long)Mc * 128 + 255) / 256), 256, 0, stream>>>(
          C2b, ea_cur + e0 * 64, C3b, (long)Mc * 128);
      mg2_k<true, false, false, true><<<g1m, 256, 0, stream>>>(
          C3b, nullptr, nullptr, euW1t, eu_b1, C1b, Mc, 128, 128, 128, 128);
      mgemm_k<false, false, false, false><<<g64, 256, 0, stream>>>(
          C1b, nullptr, nullptr, euW2t, eu_b2, EAp + e0 * 64, Mc, 64, 128, 128, 64);
    }
    f2b_kernel<<<(E_ * 64 + 255) / 256, 256, 0, stream>>>(EAp, eab, E_ * 64);

    x_cur = Hb;
    ea_cur = EAp;
  }

  // outputs: [out (N*128) | ea (in place) | out (N*128)]
  hipMemcpyAsync(out, x_cur, (size_t)N_ * 128 * 4, hipMemcpyDeviceToDevice, stream);
  hipMemcpyAsync(out + (size_t)N_ * 128 + (size_t)E_ * 64, x_cur,
                 (size_t)N_ * 128 * 4, hipMemcpyDeviceToDevice, stream);
}

// Round 8
// 2865.575 us; speedup vs baseline: 1.0902x; 1.0902x over previous
//
#include <hip/hip_runtime.h>
#include <hip/hip_bf16.h>
#include <math.h>

#define GN 10000
#define GNP 10112        // GN padded to 128
#define GE 160000
#define GT 4
#define GL 3

typedef __attribute__((ext_vector_type(8))) short short8;
typedef __attribute__((ext_vector_type(4))) float f32x4;
typedef unsigned short u16;
typedef unsigned int u32;

__device__ __forceinline__ u16 f2b(float f) {
  unsigned u = __float_as_uint(f);
  unsigned r = (u + 0x7FFFu + ((u >> 16) & 1u)) >> 16;
  return (u16)r;
}
__device__ __forceinline__ float b2f(u16 b) {
  return __uint_as_float(((unsigned)b) << 16);
}

// async global->LDS, 16B per lane; lds dest must be wave-uniform base
__device__ __forceinline__ void gl_lds16(const void* g, void* l) {
  __builtin_amdgcn_global_load_lds(
      (const __attribute__((address_space(1))) void*)g,
      (__attribute__((address_space(3))) void*)l, 16, 0, 0);
}

// ---------------------------------------------------------------------------
// fp32 tiled GEMM (only the tiny 32x32 post-W2 uses this)
// ---------------------------------------------------------------------------
template<bool RELU_C, bool GATHER, bool OUTB>
__global__ __launch_bounds__(256) void gemm_k(
    const float* __restrict__ A, const int* __restrict__ idx,
    const float* __restrict__ B, const float* __restrict__ bias,
    void* __restrict__ Cv,
    int M, int N, int K, int lda, int ldb, int ldc)
{
  __shared__ float As[16][65];
  __shared__ float Bs[16][65];
  const int tid = threadIdx.x;
  const int brow = blockIdx.y * 64, bcol = blockIdx.x * 64;
  const int tr = ((tid >> 4) & 15) << 2;
  const int tc = (tid & 15) << 2;
  float acc[4][4] = {{0.f}};

  for (int k0 = 0; k0 < K; k0 += 16) {
    for (int i = tid; i < 64 * 16; i += 256) {
      int r = i >> 4, c = i & 15;
      int gr = brow + r, gk = k0 + c;
      float v = 0.f;
      if (gr < M && gk < K) {
        size_t ar = GATHER ? (size_t)idx[gr] : (size_t)gr;
        v = A[ar * (size_t)lda + gk];
      }
      As[c][r] = v;
    }
    for (int i = tid; i < 16 * 64; i += 256) {
      int r = i >> 6, c = i & 63;
      int gk = k0 + r, gc = bcol + c;
      Bs[r][c] = (gk < K && gc < N) ? B[(size_t)gk * ldb + gc] : 0.f;
    }
    __syncthreads();
#pragma unroll
    for (int kk = 0; kk < 16; ++kk) {
      float a[4], b[4];
#pragma unroll
      for (int i = 0; i < 4; ++i) a[i] = As[kk][tr + i];
#pragma unroll
      for (int j = 0; j < 4; ++j) b[j] = Bs[kk][tc + j];
#pragma unroll
      for (int i = 0; i < 4; ++i)
#pragma unroll
        for (int j = 0; j < 4; ++j) acc[i][j] += a[i] * b[j];
    }
    __syncthreads();
  }

#pragma unroll
  for (int i = 0; i < 4; ++i) {
    int gr = brow + tr + i;
    if (gr >= M) continue;
#pragma unroll
    for (int j = 0; j < 4; ++j) {
      int gc = bcol + tc + j;
      if (gc >= N) continue;
      float v = acc[i][j] + bias[gc];
      if (RELU_C) v = fmaxf(v, 0.f);
      if (OUTB) ((u16*)Cv)[(size_t)gr * ldc + gc] = f2b(v);
      else      ((float*)Cv)[(size_t)gr * ldc + gc] = v;
    }
  }
}

// ---------------------------------------------------------------------------
// bf16 MFMA GEMM, 64x64 tile (kept for N=64 outputs: postW1)
// ---------------------------------------------------------------------------
template<bool RELU, bool GATHER, bool MUL, bool OUTB>
__global__ __launch_bounds__(256) void mgemm_k(
    const u16* __restrict__ A, const u16* __restrict__ A2,
    const int* __restrict__ idx,
    const u16* __restrict__ Bt, const float* __restrict__ bias,
    void* __restrict__ Cv,
    int M, int N, int K, int lda, int ldc)
{
  __shared__ u16 As[64 * 64];
  __shared__ u16 Bs[64 * 64];
  __shared__ int ridx[64];
  const int tid = threadIdx.x;
  const int brow = blockIdx.y * 64, bcol = blockIdx.x * 64;
  const int wid = tid >> 6, lane = tid & 63;
  const int wr = wid >> 1, wc = wid & 1;
  const int lrow = lane & 15, lk8 = (lane >> 4) * 8;

  if (tid < 64) ridx[tid] = GATHER ? idx[brow + tid] : (brow + tid);
  __syncthreads();

  f32x4 acc[2][2] = {};

  for (int k0 = 0; k0 < K; k0 += 64) {
#pragma unroll
    for (int s = 0; s < 2; ++s) {
      int c = tid + s * 256;
      int r = c >> 3, kq = (c & 7) * 8;
      const u16* sp = A + (size_t)ridx[r] * lda + k0 + kq;
      short8 v = *(const short8*)sp;
      if (MUL) {
        const u16* sp2 = A2 + (size_t)ridx[r] * lda + k0 + kq;
        short8 v2 = *(const short8*)sp2;
#pragma unroll
        for (int e = 0; e < 8; ++e)
          v[e] = (short)f2b(b2f((u16)v[e]) * b2f((u16)v2[e]));
      }
      int byt = (r * 128 + kq * 2) ^ ((r & 7) << 4);
      *(short8*)((char*)As + byt) = v;
    }
#pragma unroll
    for (int s = 0; s < 2; ++s) {
      int c = tid + s * 256;
      int r = c >> 3, kq = (c & 7) * 8;
      const u16* sp = Bt + (size_t)(bcol + r) * K + k0 + kq;
      short8 v = *(const short8*)sp;
      int byt = (r * 128 + kq * 2) ^ ((r & 7) << 4);
      *(short8*)((char*)Bs + byt) = v;
    }
    __syncthreads();
#pragma unroll
    for (int ks = 0; ks < 2; ++ks) {
      short8 a[2], b[2];
#pragma unroll
      for (int m = 0; m < 2; ++m) {
        int r = wr * 32 + m * 16 + lrow;
        int kk = ks * 32 + lk8;
        int byt = (r * 128 + kk * 2) ^ ((r & 7) << 4);
        a[m] = *(const short8*)((const char*)As + byt);
      }
#pragma unroll
      for (int n = 0; n < 2; ++n) {
        int r = wc * 32 + n * 16 + lrow;
        int kk = ks * 32 + lk8;
        int byt = (r * 128 + kk * 2) ^ ((r & 7) << 4);
        b[n] = *(const short8*)((const char*)Bs + byt);
      }
#pragma unroll
      for (int m = 0; m < 2; ++m)
#pragma unroll
        for (int n = 0; n < 2; ++n)
          acc[m][n] = __builtin_amdgcn_mfma_f32_16x16x32_bf16(a[m], b[n], acc[m][n], 0, 0, 0);
    }
    __syncthreads();
  }

#pragma unroll
  for (int m = 0; m < 2; ++m)
#pragma unroll
    for (int n = 0; n < 2; ++n) {
      int col = bcol + wc * 32 + n * 16 + (lane & 15);
      float bv = bias[col];
#pragma unroll
      for (int j = 0; j < 4; ++j) {
        int row = brow + wr * 32 + m * 16 + (lane >> 4) * 4 + j;
        float v = acc[m][n][j] + bv;
        if (RELU) v = fmaxf(v, 0.f);
        if (OUTB) ((u16*)Cv)[(size_t)row * ldc + col] = f2b(v);
        else      ((float*)Cv)[(size_t)row * ldc + col] = v;
      }
    }
}

// ---------------------------------------------------------------------------
// bf16 MFMA GEMM, 128x128 tile (conv + node GEMMs). gload_lds staging.
// ---------------------------------------------------------------------------
template<bool RELU, bool GATHER, bool MUL, bool OUTB>
__global__ __launch_bounds__(256) void mg2_k(
    const u16* __restrict__ A, const u16* __restrict__ A2,
    const int* __restrict__ idx,
    const u16* __restrict__ Bt, const float* __restrict__ bias,
    void* __restrict__ Cv,
    int M, int N, int K, int lda, int ldc)
{
  __shared__ u16 As[128 * 64];
  __shared__ u16 Bs[128 * 64];
  __shared__ int ridx[128];
  const int tid = threadIdx.x;
  const int brow = blockIdx.y * 128, bcol = blockIdx.x * 128;
  const int wid = tid >> 6, lane = tid & 63;
  const int wr = wid >> 1, wc = wid & 1;
  const int lrow = lane & 15, lkg = lane >> 4;

  if (GATHER) {
    if (tid < 128) ridx[tid] = idx[brow + tid];
    __syncthreads();
  }

  f32x4 acc[4][4] = {};

  const char* srcA[4];
  const char* srcB[4];
#pragma unroll
  for (int s = 0; s < 4; ++s) {
    int i = tid + s * 256;
    int r = i >> 3, g = i & 7;
    size_t grow = GATHER ? (size_t)ridx[r] : (size_t)(brow + r);
    int gq = (g ^ (r & 7)) * 8;
    srcA[s] = (const char*)(A + grow * lda + gq);
    srcB[s] = (const char*)(Bt + (size_t)(bcol + r) * K + gq);
  }

  for (int k0 = 0; k0 < K; k0 += 64) {
    if constexpr (!MUL) {
#pragma unroll
      for (int s = 0; s < 4; ++s)
        gl_lds16(srcA[s] + (size_t)k0 * 2, (char*)As + s * 4096 + wid * 1024);
#pragma unroll
      for (int s = 0; s < 4; ++s)
        gl_lds16(srcB[s] + (size_t)k0 * 2, (char*)Bs + s * 4096 + wid * 1024);
    } else {
#pragma unroll
      for (int s = 0; s < 4; ++s) {
        int i = tid + s * 256;
        int r = i >> 3, kq = (i & 7) * 8;
        size_t grow = GATHER ? (size_t)ridx[r] : (size_t)(brow + r);
        const u16* sp = A + grow * lda + k0 + kq;
        short8 v = *(const short8*)sp;
        const u16* sp2 = A2 + grow * lda + k0 + kq;
        short8 v2 = *(const short8*)sp2;
#pragma unroll
        for (int e = 0; e < 8; ++e)
          v[e] = (short)f2b(b2f((u16)v[e]) * b2f((u16)v2[e]));
        int byt = (r * 128 + kq * 2) ^ ((r & 7) << 4);
        *(short8*)((char*)As + byt) = v;
      }
#pragma unroll
      for (int s = 0; s < 4; ++s) {
        int i = tid + s * 256;
        int r = i >> 3, kq = (i & 7) * 8;
        const u16* sp = Bt + (size_t)(bcol + r) * K + k0 + kq;
        short8 v = *(const short8*)sp;
        int byt = (r * 128 + kq * 2) ^ ((r & 7) << 4);
        *(short8*)((char*)Bs + byt) = v;
      }
    }
    __syncthreads();
#pragma unroll
    for (int ks = 0; ks < 2; ++ks) {
      const int kb = ks * 64 + lkg * 16;
      short8 a[4], b[4];
#pragma unroll
      for (int m = 0; m < 4; ++m) {
        int r = wr * 64 + m * 16 + lrow;
        int byt = (r * 128 + kb) ^ ((r & 7) << 4);
        a[m] = *(const short8*)((const char*)As + byt);
      }
#pragma unroll
      for (int n = 0; n < 4; ++n) {
        int r = wc * 64 + n * 16 + lrow;
        int byt = (r * 128 + kb) ^ ((r & 7) << 4);
        b[n] = *(const short8*)((const char*)Bs + byt);
      }
#pragma unroll
      for (int m = 0; m < 4; ++m)
#pragma unroll
        for (int n = 0; n < 4; ++n)
          acc[m][n] = __builtin_amdgcn_mfma_f32_16x16x32_bf16(a[m], b[n], acc[m][n], 0, 0, 0);
    }
    __syncthreads();
  }

#pragma unroll
  for (int m = 0; m < 4; ++m)
#pragma unroll
    for (int n = 0; n < 4; ++n) {
      int col = bcol + wc * 64 + n * 16 + lrow;
      float bv = bias[col];
#pragma unroll
      for (int j = 0; j < 4; ++j) {
        int row = brow + wr * 64 + m * 16 + lkg * 4 + j;
        float v = acc[m][n][j] + bv;
        if (RELU) v = fmaxf(v, 0.f);
        if (OUTB) ((u16*)Cv)[(size_t)row * ldc + col] = f2b(v);
        else      ((float*)Cv)[(size_t)row * ldc + col] = v;
      }
    }
}

// ===========================================================================
// FUSED EDGE-UPDATE KERNEL: per 64-edge tile, whole 9-op MLP chain in LDS.
// 256 thr = 4 waves. Wave mapping per 128-col unit: rows (w>>1)*32, cols (w&1)*64.
// All LDS tiles XOR-swizzled: byte ^= (row&7)<<4.
// ===========================================================================
__device__ __forceinline__ void ef_stage_w(const u16* __restrict__ Wt, int KK,
                                           int gcol0, int ncols, int k0,
                                           u16* Wb, int tid)
{
  const int wid = tid >> 6;
  const int rounds = ncols >> 5;       // ncols*8 granules / 256 threads
  for (int s = 0; s < rounds; ++s) {
    int i = s * 256 + tid;
    int col = i >> 3, g = i & 7;
    const u16* sp = Wt + (size_t)(gcol0 + col) * KK + k0 + ((g ^ (col & 7)) << 3);
    gl_lds16(sp, (char*)Wb + s * 4096 + wid * 1024);
  }
}

__device__ __forceinline__ void ef_mfma_unit(const u16* A, int astB, const u16* Wc,
                                             int k0, int wv, int lane, f32x4 acc[2][4])
{
  const int lrow = lane & 15, lkg = lane >> 4;
  const int rowBase = (wv >> 1) * 32;
  const int colBase = (wv & 1) * 64;
#pragma unroll
  for (int ks = 0; ks < 2; ++ks) {
    int kb = k0 * 2 + ks * 64 + lkg * 16;
    short8 a[2], b[4];
#pragma unroll
    for (int m = 0; m < 2; ++m) {
      int r = rowBase + m * 16 + lrow;
      int byt = (r * astB + kb) ^ ((r & 7) << 4);
      a[m] = *(const short8*)((const char*)A + byt);
    }
#pragma unroll
    for (int n = 0; n < 4; ++n) {
      int c = colBase + n * 16 + lrow;
      int byt = (c * 128 + ks * 64 + lkg * 16) ^ ((c & 7) << 4);
      b[n] = *(const short8*)((const char*)Wc + byt);
    }
#pragma unroll
    for (int m = 0; m < 2; ++m)
#pragma unroll
      for (int n = 0; n < 4; ++n)
        acc[m][n] = __builtin_amdgcn_mfma_f32_16x16x32_bf16(a[m], b[n], acc[m][n], 0, 0, 0);
  }
}

template<int KK>
__device__ __forceinline__ void ef_phase(const u16* A, int astB,
    const u16* __restrict__ Wt, int gcol0, int ncols,
    u16* W0, u16* W1, int tid, f32x4 acc[2][4])
{
  const int wv = tid >> 6, lane = tid & 63;
#pragma unroll
  for (int m = 0; m < 2; ++m)
#pragma unroll
    for (int n = 0; n < 4; ++n) acc[m][n] = (f32x4){0.f, 0.f, 0.f, 0.f};
  ef_stage_w(Wt, KK, gcol0, ncols, 0, W0, tid);
  __syncthreads();
  const bool active = ((wv & 1) * 64) < ncols;
#pragma unroll
  for (int step = 0; step < KK / 64; ++step) {
    u16* cur = (step & 1) ? W1 : W0;
    if (step + 1 < KK / 64)
      ef_stage_w(Wt, KK, gcol0, ncols, (step + 1) * 64, ((step + 1) & 1) ? W1 : W0, tid);
    if (active) ef_mfma_unit(A, astB, cur, step * 64, wv, lane, acc);
    __syncthreads();
  }
}

// write acc -> LDS buffer (bf16, swizzled), cols [ocol0 + (w&1)*64 ...]
template<bool RELU>
__device__ __forceinline__ void ef_out_lds(f32x4 acc[2][4], const float* bias, int bcol0,
    u16* O, int ostB, int ocol0, int ncols, int tid)
{
  const int wv = tid >> 6, lane = tid & 63;
  const int lrow = lane & 15, lkg = lane >> 4;
  const int rowBase = (wv >> 1) * 32, colBase = (wv & 1) * 64;
  if (colBase >= ncols) return;
#pragma unroll
  for (int m = 0; m < 2; ++m)
#pragma unroll
    for (int n = 0; n < 4; ++n) {
      int c = colBase + n * 16 + lrow;
      float bv = bias[bcol0 + c];
#pragma unroll
      for (int j = 0; j < 4; ++j) {
        int r = rowBase + m * 16 + lkg * 4 + j;
        float v = acc[m][n][j] + bv;
        if (RELU) v = fmaxf(v, 0.f);
        int byt = (r * ostB + (ocol0 + c) * 2) ^ ((r & 7) << 4);
        *(u16*)((char*)O + byt) = f2b(v);
      }
    }
}

__global__ __launch_bounds__(256) void edge_fused_kernel(
    const u16* __restrict__ xb, const int* __restrict__ src, const int* __restrict__ dst,
    const float* __restrict__ ea,
    const u16* __restrict__ fcuW1t, const float* __restrict__ fcu_b1,
    const u16* __restrict__ fcuW2t, const float* __restrict__ fcu_b2,
    const u16* __restrict__ fcvW1t, const float* __restrict__ fcv_b1,
    const u16* __restrict__ fcvW2t, const float* __restrict__ fcv_b2,
    const u16* __restrict__ fcW1t,  const float* __restrict__ fc_b1,
    const u16* __restrict__ fcW2t,  const float* __restrict__ fc_b2,
    const u16* __restrict__ euW1t,  const float* __restrict__ eu_b1,
    const u16* __restrict__ euW2t,  const float* __restrict__ eu_b2,
    float* __restrict__ eaOut, u16* __restrict__ eabOut)
{
  __shared__ u16 X[64 * 128];     // 16 KB  (x rows; later ecat = [med|ea])
  __shared__ u16 B1[64 * 256];    // 32 KB
  __shared__ u16 B2[64 * 256];    // 32 KB
  __shared__ u16 B3[64 * 256];    // 32 KB
  __shared__ u16 W0[128 * 64];    // 16 KB
  __shared__ u16 W1[128 * 64];    // 16 KB
  __shared__ int sid[64], did[64];

  const int tid = threadIdx.x;
  const long e0 = (long)blockIdx.x * 64;
  const int wid = tid >> 6;

  if (tid < 64) { sid[tid] = src[e0 + tid]; did[tid] = dst[e0 + tid]; }
  __syncthreads();

  f32x4 acc[2][4];

  // ---- load X = x[src] (gl_lds, linear dest, source granule pre-swizzled) ----
#pragma unroll
  for (int s = 0; s < 4; ++s) {
    int i = s * 256 + tid;
    int row = i >> 4, g = i & 15;
    int gs = (g & 8) | ((g & 7) ^ (row & 7));
    gl_lds16(xb + (size_t)sid[row] * 128 + gs * 8, (char*)X + s * 4096 + wid * 1024);
  }
  __syncthreads();

  // ---- u1 = relu(X @ fcuW1^T + b) -> B1 (256 cols, two 128-col units) ----
  ef_phase<128>(X, 256, fcuW1t, 0, 128, W0, W1, tid, acc);
  ef_out_lds<true>(acc, fcu_b1, 0, B1, 512, 0, 128, tid);
  ef_phase<128>(X, 256, fcuW1t, 128, 128, W0, W1, tid, acc);
  ef_out_lds<true>(acc, fcu_b1, 128, B1, 512, 128, 128, tid);

  // ---- u2 = relu(B1 @ fcuW2^T + b) -> B2 ----
  ef_phase<256>(B1, 512, fcuW2t, 0, 128, W0, W1, tid, acc);
  ef_out_lds<true>(acc, fcu_b2, 0, B2, 512, 0, 128, tid);
  ef_phase<256>(B1, 512, fcuW2t, 128, 128, W0, W1, tid, acc);
  ef_out_lds<true>(acc, fcu_b2, 128, B2, 512, 128, 128, tid);
  __syncthreads();   // B1 reads complete before X... (X reload is next, B1 reuse after)

  // ---- reload X = x[dst] ----
#pragma unroll
  for (int s = 0; s < 4; ++s) {
    int i = s * 256 + tid;
    int row = i >> 4, g = i & 15;
    int gs = (g & 8) | ((g & 7) ^ (row & 7));
    gl_lds16(xb + (size_t)did[row] * 128 + gs * 8, (char*)X + s * 4096 + wid * 1024);
  }
  __syncthreads();

  // ---- v1 = relu(X @ fcvW1^T + b) -> B1 ----
  ef_phase<128>(X, 256, fcvW1t, 0, 128, W0, W1, tid, acc);
  ef_out_lds<true>(acc, fcv_b1, 0, B1, 512, 0, 128, tid);
  ef_phase<128>(X, 256, fcvW1t, 128, 128, W0, W1, tid, acc);
  ef_out_lds<true>(acc, fcv_b1, 128, B1, 512, 128, 128, tid);

  // ---- v2 = relu(B1 @ fcvW2^T + b) -> B3 ----
  ef_phase<256>(B1, 512, fcvW2t, 0, 128, W0, W1, tid, acc);
  ef_out_lds<true>(acc, fcv_b2, 0, B3, 512, 0, 128, tid);
  ef_phase<256>(B1, 512, fcvW2t, 128, 128, W0, W1, tid, acc);
  ef_out_lds<true>(acc, fcv_b2, 128, B3, 512, 128, 128, tid);
  __syncthreads();   // B2/B3 writes visible for P

  // ---- P = u2 .* v2 -> B1 (raw-layout elementwise; same swizzle all three) ----
#pragma unroll
  for (int s = 0; s < 32; ++s) {
    int i = tid + s * 256;
    u32 a = ((const u32*)B2)[i], b = ((const u32*)B3)[i];
    float lo = b2f((u16)(a & 0xffff)) * b2f((u16)(b & 0xffff));
    float hi = b2f((u16)(a >> 16)) * b2f((u16)(b >> 16));
    ((u32*)B1)[i] = (u32)f2b(lo) | ((u32)f2b(hi) << 16);
  }
  __syncthreads();

  // ---- fc1 = relu(P @ fcW1^T + b) -> B2 ----
  ef_phase<256>(B1, 512, fcW1t, 0, 128, W0, W1, tid, acc);
  ef_out_lds<true>(acc, fc_b1, 0, B2, 512, 0, 128, tid);
  ef_phase<256>(B1, 512, fcW1t, 128, 128, W0, W1, tid, acc);
  ef_out_lds<true>(acc, fc_b1, 128, B2, 512, 128, 128, tid);
  __syncthreads();   // X reads (v1) long done; X now rebuilt as ecat

  // ---- ecat cols 64..127 <- bf16(ea rows) ----
#pragma unroll
  for (int s = 0; s < 4; ++s) {
    int i = tid + s * 256;
    int row = i >> 4, c0 = (i & 15) * 4;
    float4 v = *(const float4*)(ea + (e0 + row) * 64 + c0);
    ushort4 h;
    h.x = f2b(v.x); h.y = f2b(v.y); h.z = f2b(v.z); h.w = f2b(v.w);
    int byt = (row * 256 + (64 + c0) * 2) ^ ((row & 7) << 4);
    *(ushort4*)((char*)X + byt) = h;
  }

  // ---- med = relu(fc1 @ fcW2^T + b) -> ecat cols 0..63 ----
  ef_phase<256>(B2, 512, fcW2t, 0, 64, W0, W1, tid, acc);
  ef_out_lds<true>(acc, fc_b2, 0, X, 256, 0, 64, tid);
  __syncthreads();   // ecat complete

  // ---- eu1 = relu(ecat @ euW1^T + b) -> B1 (64x128, stride 256) ----
  ef_phase<128>(X, 256, euW1t, 0, 128, W0, W1, tid, acc);
  ef_out_lds<true>(acc, eu_b1, 0, B1, 256, 0, 128, tid);
  __syncthreads();

  // ---- ea_out = B1 @ euW2^T + b -> global (fp32 + bf16) ----
  ef_phase<128>(B1, 256, euW2t, 0, 64, W0, W1, tid, acc);
  {
    const int wv = tid >> 6, lane = tid & 63;
    const int lrow = lane & 15, lkg = lane >> 4;
    const int rowBase = (wv >> 1) * 32, colBase = (wv & 1) * 64;
    if (colBase < 64) {
#pragma unroll
      for (int m = 0; m < 2; ++m)
#pragma unroll
        for (int n = 0; n < 4; ++n) {
          int c = n * 16 + lrow;
          float bv = eu_b2[c];
#pragma unroll
          for (int j = 0; j < 4; ++j) {
            int r = rowBase + m * 16 + lkg * 4 + j;
            float v = acc[m][n][j] + bv;
            size_t o = (size_t)(e0 + r) * 64 + c;
            eaOut[o] = v;
            eabOut[o] = f2b(v);
          }
        }
    }
  }
}

// ---------------------------------------------------------------------------
// Edge sort by dst (counting sort)
// ---------------------------------------------------------------------------
__global__ void deg_kernel(const int* __restrict__ dst, int* __restrict__ deg, int E)
{
  int e = blockIdx.x * blockDim.x + threadIdx.x;
  if (e < E) atomicAdd(&deg[dst[e]], 1);
}

__global__ void scan_kernel(const int* __restrict__ deg, int* __restrict__ rowptr, int n)
{
  __shared__ int tmp[256];
  __shared__ int carry;
  if (threadIdx.x == 0) carry = 0;
  __syncthreads();
  for (int base = 0; base < n; base += 256) {
    int i = base + (int)threadIdx.x;
    int v = (i < n) ? deg[i] : 0;
    tmp[threadIdx.x] = v;
    __syncthreads();
    for (int off = 1; off < 256; off <<= 1) {
      int t = (threadIdx.x >= (unsigned)off) ? tmp[threadIdx.x - off] : 0;
      __syncthreads();
      tmp[threadIdx.x] += t;
      __syncthreads();
    }
    if (i < n) rowptr[i] = carry + tmp[threadIdx.x] - v;
    __syncthreads();
    if (threadIdx.x == 0) carry += tmp[255];
    __syncthreads();
  }
  if (threadIdx.x == 0) rowptr[n] = carry;
}

__global__ void scatter_kernel(const int* __restrict__ dst, int* __restrict__ cursor,
                               int* __restrict__ eidx, int E)
{
  int e = blockIdx.x * blockDim.x + threadIdx.x;
  if (e < E) {
    int p = atomicAdd(&cursor[dst[e]], 1);
    eidx[p] = e;
  }
}

// ---------------------------------------------------------------------------
// Batched weight transpose+convert: W[b] (K x N fp32) -> Wt[b] (N x K bf16)
// ---------------------------------------------------------------------------
__global__ void wtb_kernel(const float* __restrict__ W, u16* __restrict__ Wt,
                           int K, int N, size_t wtStride)
{
  int b = blockIdx.y;
  const float* Wb = W + (size_t)b * K * N;
  u16* Wtb = Wt + (size_t)b * wtStride;
  for (int i = blockIdx.x * blockDim.x + threadIdx.x; i < K * N;
       i += gridDim.x * blockDim.x) {
    int k = i / N, n = i % N;
    Wtb[(size_t)n * K + k] = f2b(Wb[i]);
  }
}

__global__ void biaspad_kernel(const float* __restrict__ b32, float* __restrict__ b64, int total)
{
  int i = blockIdx.x * blockDim.x + threadIdx.x;
  if (i >= total) return;
  b64[(i / 32) * 64 + (i % 32)] = b32[i];
}

__global__ void f2b_kernel(const float* __restrict__ in, u16* __restrict__ out, int n)
{
  int i = blockIdx.x * blockDim.x + threadIdx.x;
  if (i < n) out[i] = f2b(in[i]);
}

// ---------------------------------------------------------------------------
// Build Acat (bf16) cols 0..255 for a chunk (sorted order): [xb[dst] | xb[src]]
// ---------------------------------------------------------------------------
__global__ void build_acat_kernel(const u16* __restrict__ xb,
                                  const int* __restrict__ eidx,
                                  const int* __restrict__ srcA,
                                  const int* __restrict__ dstA,
                                  long base, int Mc, u16* __restrict__ Acat)
{
  int i = blockIdx.x * blockDim.x + threadIdx.x;
  int total = Mc * 32;
  if (i >= total) return;
  int p = i >> 5, q = i & 31;
  int e = eidx[base + p];
  int c0 = q * 8;
  const u16* sp = (c0 < 128) ? (xb + (size_t)dstA[e] * 128 + c0)
                             : (xb + (size_t)srcA[e] * 128 + (c0 - 128));
  *(int4*)(Acat + (size_t)p * 384 + c0) = *(const int4*)sp;
}

// ---------------------------------------------------------------------------
// Aggregator init
// ---------------------------------------------------------------------------
__global__ void agg_init_kernel(float* __restrict__ s, float* __restrict__ ss,
                                unsigned* __restrict__ mx, int total)
{
  int i = blockIdx.x * blockDim.x + threadIdx.x;
  if (i >= total) return;
  s[i] = 0.f; ss[i] = 0.f; mx[i] = 0x007FFFFFu;
}

// ---------------------------------------------------------------------------
// Sorted-segment merge (bf16 msg, all 4 towers via blockIdx.y)
// ---------------------------------------------------------------------------
__global__ __launch_bounds__(128) void agg_merge_kernel(
    const u16* __restrict__ msgb, size_t msgStride,
    const int* __restrict__ eidx, const int* __restrict__ dst, long base,
    float* __restrict__ sumb, float* __restrict__ sumsqb,
    unsigned* __restrict__ mxb, int Nn)
{
  __shared__ int nid[64];
  const int t = blockIdx.y;
  const u16* msg = msgb + (size_t)t * msgStride;
  float* sb = sumb + (size_t)t * Nn * 128;
  float* qb = sumsqb + (size_t)t * Nn * 128;
  unsigned* xb_ = mxb + (size_t)t * Nn * 128;
  const int tid = threadIdx.x;
  const long p0 = (long)blockIdx.x * 64;
  if (tid < 64) nid[tid] = dst[eidx[base + p0 + tid]];
  __syncthreads();
  int col = tid;
  int cur = nid[0];
  float s = 0.f, ssq = 0.f, m = -INFINITY;
  for (int rr = 0; rr < 64; ++rr) {
    int n = nid[rr];
    if (n != cur) {
      size_t o = (size_t)cur * 128 + col;
      atomicAdd(&sb[o], s);
      atomicAdd(&qb[o], ssq);
      unsigned ub = __float_as_uint(m);
      atomicMax(&xb_[o], (ub & 0x80000000u) ? ~ub : (ub | 0x80000000u));
      cur = n; s = 0.f; ssq = 0.f; m = -INFINITY;
    }
    float v = b2f(msg[(size_t)(p0 + rr) * 128 + col]);
    s += v; ssq += v * v; m = fmaxf(m, v);
  }
  size_t o = (size_t)cur * 128 + col;
  atomicAdd(&sb[o], s);
  atomicAdd(&qb[o], ssq);
  unsigned ub = __float_as_uint(m);
  atomicMax(&xb_[o], (ub & 0x80000000u) ? ~ub : (ub | 0x80000000u));
}

// ---------------------------------------------------------------------------
// Finalize (per tower): write bf16 cat tile [x | mean | max | std] (N x 512)
// ---------------------------------------------------------------------------
__global__ void finalize_kernel(
    const float* __restrict__ sumb, const float* __restrict__ sumsqb,
    const unsigned* __restrict__ mxb, const int* __restrict__ rowptr,
    const float* __restrict__ x, u16* __restrict__ catb, int total)
{
  int i = blockIdx.x * blockDim.x + threadIdx.x;
  if (i >= total) return;               // total = N*128
  int n = i >> 7, c = i & 127;
  float cnt = fmaxf((float)(rowptr[n + 1] - rowptr[n]), 1.f);
  float mean = sumb[i] / cnt;
  float msq  = sumsqb[i] / cnt;
  float sd = sqrtf(fmaxf(msq - mean * mean, 0.f) + 1e-5f);
  unsigned u = mxb[i];
  unsigned bits = (u & 0x80000000u) ? (u & 0x7FFFFFFFu) : ~u;
  float mxv = __uint_as_float(bits);
  if ((bits & 0x7F800000u) == 0x7F800000u) mxv = 0.f;
  u16* cb = catb + (size_t)n * 512;
  cb[c]       = f2b(x[(size_t)n * 128 + c]);
  cb[128 + c] = f2b(mean);
  cb[256 + c] = f2b(mxv);
  cb[384 + c] = f2b(sd);
}

// ---------------------------------------------------------------------------
// GRU elementwise combine
// ---------------------------------------------------------------------------
__global__ void gru_kernel(const float* __restrict__ gi, const float* __restrict__ gh,
                           const float* __restrict__ h, float* __restrict__ hout, int total)
{
  int i = blockIdx.x * blockDim.x + threadIdx.x;
  if (i >= total) return;
  int n = i >> 7, c = i & 127;
  const float* gin = gi + (size_t)n * 384;
  const float* ghn = gh + (size_t)n * 384;
  float ir = gin[c], iz = gin[128 + c], inn = gin[256 + c];
  float hr = ghn[c], hz = ghn[128 + c], hn = ghn[256 + c];
  float r = 1.f / (1.f + __expf(-(ir + hr)));
  float z = 1.f / (1.f + __expf(-(iz + hz)));
  float nn = tanhf(inn + r * hn);
  hout[i] = (1.f - z) * nn + z * h[i];
}

// ---------------------------------------------------------------------------
extern "C" void kernel_launch(void* const* d_in, const int* in_sizes, int n_in,
                              void* d_out, int out_size, void* d_ws, size_t ws_size,
                              hipStream_t stream)
{
  const int N_ = GN, E_ = GE, Np = GNP;

  const float* x_in   = (const float*)d_in[0];
  const int*   src    = (const int*)d_in[1];
  const int*   dst    = src + E_;
  const float* ea_in  = (const float*)d_in[2];
  const float* enc_W  = (const float*)d_in[3];
  const float* enc_b  = (const float*)d_in[4];
  const float* pre_W1 = (const float*)d_in[5];
  const float* pre_b1 = (const float*)d_in[6];
  const float* pre_W2 = (const float*)d_in[7];
  const float* pre_b2 = (const float*)d_in[8];
  const float* post_W1 = (const float*)d_in[9];
  const float* post_b1 = (const float*)d_in[10];
  const float* post_W2 = (const float*)d_in[11];
  const float* post_b2 = (const float*)d_in[12];
  const float* lin_W  = (const float*)d_in[13];
  const float* lin_b  = (const float*)d_in[14];
  const float* gru_Wi = (const float*)d_in[15];
  const float* gru_Wh = (const float*)d_in[16];
  const float* gru_bi = (const float*)d_in[17];
  const float* gru_bh = (const float*)d_in[18];
  const float* fcu_W1 = (const float*)d_in[19];
  const float* fcu_b1 = (const float*)d_in[20];
  const float* fcu_W2 = (const float*)d_in[21];
  const float* fcu_b2 = (const float*)d_in[22];
  const float* fcv_W1 = (const float*)d_in[23];
  const float* fcv_b1 = (const float*)d_in[24];
  const float* fcv_W2 = (const float*)d_in[25];
  const float* fcv_b2 = (const float*)d_in[26];
  const float* fc_W1  = (const float*)d_in[27];
  const float* fc_b1  = (const float*)d_in[28];
  const float* fc_W2  = (const float*)d_in[29];
  const float* fc_b2  = (const float*)d_in[30];
  const float* eu_W1  = (const float*)d_in[31];
  const float* eu_b1  = (const float*)d_in[32];
  const float* eu_W2  = (const float*)d_in[33];
  const float* eu_b2  = (const float*)d_in[34];

  // ---- workspace arena ----
  size_t used = 0;
  char* w = (char*)d_ws;
  auto alloc = [&](size_t bytes) {
    char* p = w + used;
    used += (bytes + 255) & ~(size_t)255;
    return p;
  };
  float*    sumb   = (float*)alloc((size_t)N_ * 512 * 4);   // [t][n][128]
  float*    sumsqb = (float*)alloc((size_t)N_ * 512 * 4);
  unsigned* mxb    = (unsigned*)alloc((size_t)N_ * 512 * 4);
  float*    q1   = (float*)alloc((size_t)Np * 64 * 4);
  u16*      q2b  = (u16*)alloc((size_t)Np * 128 * 2);
  u16*      mbb  = (u16*)alloc((size_t)Np * 128 * 2);
  float*    gib  = (float*)alloc((size_t)Np * 384 * 4);
  float*    ghb  = (float*)alloc((size_t)Np * 384 * 4);
  float*    Hb   = (float*)alloc((size_t)N_ * 128 * 4);
  u16*      xb   = (u16*)alloc((size_t)Np * 128 * 2);
  u16*      catb = (u16*)alloc((size_t)Np * 512 * 2);
  u16*      eab  = (u16*)alloc((size_t)E_ * 64 * 2);
  // bf16 transposed weights
  u16* encWt  = (u16*)alloc((size_t)GL * 128 * 64 * 2);
  u16* preW1t = (u16*)alloc((size_t)GL * GT * 128 * 384 * 2);
  u16* preW2t = (u16*)alloc((size_t)GL * GT * 128 * 128 * 2);
  u16* postW1t = (u16*)alloc((size_t)GL * GT * 64 * 512 * 2);
  float* postb1p = (float*)alloc((size_t)GL * GT * 64 * 4);
  u16* linWt  = (u16*)alloc((size_t)GL * 128 * 128 * 2);
  u16* gruWit = (u16*)alloc((size_t)384 * 128 * 2);
  u16* gruWht = (u16*)alloc((size_t)384 * 128 * 2);
  u16* fcuW1t = (u16*)alloc((size_t)256 * 128 * 2);
  u16* fcuW2t = (u16*)alloc((size_t)256 * 256 * 2);
  u16* fcvW1t = (u16*)alloc((size_t)256 * 128 * 2);
  u16* fcvW2t = (u16*)alloc((size_t)256 * 256 * 2);
  u16* fcW1t  = (u16*)alloc((size_t)256 * 256 * 2);
  u16* fcW2t  = (u16*)alloc((size_t)64 * 256 * 2);
  u16* euW1t  = (u16*)alloc((size_t)128 * 128 * 2);
  u16* euW2t  = (u16*)alloc((size_t)64 * 128 * 2);
  int* eidx   = (int*)alloc((size_t)E_ * 4);
  int* degb   = (int*)alloc((size_t)(N_ + 1) * 4);
  int* rowptr = (int*)alloc((size_t)(N_ + 1) * 4);
  int* cursor = (int*)alloc((size_t)(N_ + 1) * 4);

  // conv chunk arena: 2048 B/row (hball 1024 | Acat 768 -> msgb 4x256)
  size_t avail = (ws_size > used + 4096) ? (ws_size - used - 4096) : 0;
  long Ec = (long)(avail / 2048);
  if (Ec > E_) Ec = E_;
  Ec &= ~255L;
  if (Ec < 256) return;   // ws too small: fail cleanly
  char* arena = alloc((size_t)Ec * 2048);
  if (used > ws_size) return;
  const int nchunks = (int)((E_ + Ec - 1) / Ec);
  u16*   hball = (u16*)arena;                          // Ec x 512 bf16
  u16*   Acatb = (u16*)(arena + (size_t)Ec * 1024);    // Ec x 384 bf16
  u16*   msgb  = (u16*)(arena + (size_t)Ec * 1024);    // 4 x Ec x 128 bf16

  float* out = (float*)d_out;
  float* EAp = out + (size_t)N_ * 128;   // ea state lives in d_out

  // ---- one-time setup ----
  hipMemsetAsync(degb, 0, (size_t)N_ * 4, stream);
  deg_kernel<<<(E_ + 255) / 256, 256, 0, stream>>>(dst, degb, E_);
  scan_kernel<<<1, 256, 0, stream>>>(degb, rowptr, N_);
  hipMemcpyAsync(cursor, rowptr, (size_t)N_ * 4, hipMemcpyDeviceToDevice, stream);
  scatter_kernel<<<(E_ + 255) / 256, 256, 0, stream>>>(dst, cursor, eidx, E_);

  hipMemsetAsync(postW1t, 0, (size_t)GL * GT * 64 * 512 * 2, stream);
  hipMemsetAsync(postb1p, 0, (size_t)GL * GT * 64 * 4, stream);
  {
    dim3 gb(48, GL);
    wtb_kernel<<<gb, 256, 0, stream>>>(enc_W, encWt, 64, 128, 128 * 64);
    wtb_kernel<<<gb, 256, 0, stream>>>(lin_W, linWt, 128, 128, 128 * 128);
    dim3 gt(48, GL * GT);
    wtb_kernel<<<gt, 256, 0, stream>>>(pre_W1, preW1t, 384, 128, 128 * 384);
    wtb_kernel<<<gt, 256, 0, stream>>>(pre_W2, preW2t, 128, 128, 128 * 128);
    wtb_kernel<<<gt, 256, 0, stream>>>(post_W1, postW1t, 512, 32, 64 * 512);
    dim3 g1(48, 1);
    wtb_kernel<<<g1, 256, 0, stream>>>(gru_Wi, gruWit, 128, 384, 384 * 128);
    wtb_kernel<<<g1, 256, 0, stream>>>(gru_Wh, gruWht, 128, 384, 384 * 128);
    wtb_kernel<<<g1, 256, 0, stream>>>(fcu_W1, fcuW1t, 128, 256, 256 * 128);
    wtb_kernel<<<g1, 256, 0, stream>>>(fcu_W2, fcuW2t, 256, 256, 256 * 256);
    wtb_kernel<<<g1, 256, 0, stream>>>(fcv_W1, fcvW1t, 128, 256, 256 * 128);
    wtb_kernel<<<g1, 256, 0, stream>>>(fcv_W2, fcvW2t, 256, 256, 256 * 256);
    wtb_kernel<<<g1, 256, 0, stream>>>(fc_W1, fcW1t, 256, 256, 256 * 256);
    wtb_kernel<<<g1, 256, 0, stream>>>(fc_W2, fcW2t, 256, 64, 64 * 256);
    wtb_kernel<<<g1, 256, 0, stream>>>(eu_W1, euW1t, 128, 128, 128 * 128);
    wtb_kernel<<<g1, 256, 0, stream>>>(eu_W2, euW2t, 128, 64, 64 * 128);
  }
  biaspad_kernel<<<(GL * GT * 32 + 255) / 256, 256, 0, stream>>>(
      post_b1, postb1p, GL * GT * 32);

  f2b_kernel<<<(N_ * 128 + 255) / 256, 256, 0, stream>>>(x_in, xb, N_ * 128);
  f2b_kernel<<<(E_ * 64 + 255) / 256, 256, 0, stream>>>(ea_in, eab, E_ * 64);

  const float* x_cur = x_in;
  const float* ea_cur = ea_in;

  for (int l = 0; l < GL; ++l) {
    // ---- PNA conv ----
    agg_init_kernel<<<(N_ * 512 + 255) / 256, 256, 0, stream>>>(sumb, sumsqb, mxb, N_ * 512);
    for (int c = 0; c < nchunks; ++c) {
      long p0 = (long)c * Ec;
      int Mc = (int)(((long)E_ - p0 < Ec) ? ((long)E_ - p0) : Ec);
      dim3 gEnc(1, Mc / 128), gH(4, Mc / 128), gMsg(1, Mc / 128);
      mg2_k<false, true, false, true><<<gEnc, 256, 0, stream>>>(
          eab, nullptr, eidx + p0, encWt + (size_t)l * 128 * 64,
          enc_b + (size_t)l * 128, Acatb + 256, Mc, 128, 64, 64, 384);
      build_acat_kernel<<<(Mc * 32 + 255) / 256, 256, 0, stream>>>(
          xb, eidx, src, dst, p0, Mc, Acatb);
      mg2_k<true, false, false, true><<<gH, 256, 0, stream>>>(
          Acatb, nullptr, nullptr, preW1t + (size_t)l * 512 * 384,
          pre_b1 + (size_t)l * 512, hball, Mc, 512, 384, 384, 512);
      for (int t = 0; t < GT; ++t) {
        mg2_k<false, false, false, true><<<gMsg, 256, 0, stream>>>(
            hball + t * 128, nullptr, nullptr,
            preW2t + ((size_t)l * GT + t) * 128 * 128,
            pre_b2 + (size_t)l * 512 + t * 128,
            msgb + (size_t)t * Ec * 128, Mc, 128, 128, 512, 128);
      }
      dim3 gMg(Mc / 64, GT);
      agg_merge_kernel<<<gMg, 128, 0, stream>>>(
          msgb, (size_t)Ec * 128, eidx, dst, p0, sumb, sumsqb, mxb, N_);
    }
    for (int t = 0; t < GT; ++t) {
      finalize_kernel<<<(N_ * 128 + 255) / 256, 256, 0, stream>>>(
          sumb + (size_t)t * N_ * 128, sumsqb + (size_t)t * N_ * 128,
          mxb + (size_t)t * N_ * 128, rowptr, x_cur, catb, N_ * 128);
      dim3 gP1(1, Np / 64);
      mgemm_k<true, false, false, false><<<gP1, 256, 0, stream>>>(
          catb, nullptr, nullptr, postW1t + ((size_t)l * GT + t) * 64 * 512,
          postb1p + ((size_t)l * GT + t) * 64, q1, Np, 64, 512, 512, 64);
      dim3 gP2(1, (N_ + 63) / 64);
      gemm_k<false, false, true><<<gP2, 256, 0, stream>>>(
          q1, nullptr, post_W2 + ((size_t)l * GT + t) * 32 * 32,
          post_b2 + ((size_t)l * GT + t) * 32,
          q2b + t * 32, N_, 32, 32, 64, 32, 128);
    }
    {
      dim3 gL(1, Np / 128), gG(3, Np / 128);
      mg2_k<false, false, false, true><<<gL, 256, 0, stream>>>(
          q2b, nullptr, nullptr, linWt + (size_t)l * 128 * 128,
          lin_b + (size_t)l * 128, mbb, Np, 128, 128, 128, 128);
      mg2_k<false, false, false, false><<<gG, 256, 0, stream>>>(
          mbb, nullptr, nullptr, gruWit, gru_bi, gib, Np, 384, 128, 128, 384);
      mg2_k<false, false, false, false><<<gG, 256, 0, stream>>>(
          xb, nullptr, nullptr, gruWht, gru_bh, ghb, Np, 384, 128, 128, 384);
    }
    gru_kernel<<<(N_ * 128 + 255) / 256, 256, 0, stream>>>(gib, ghb, x_cur, Hb, N_ * 128);
    f2b_kernel<<<(N_ * 128 + 255) / 256, 256, 0, stream>>>(Hb, xb, N_ * 128);

    // ---- fused edge update: one launch, whole chain in LDS ----
    edge_fused_kernel<<<E_ / 64, 256, 0, stream>>>(
        xb, src, dst, ea_cur,
        fcuW1t, fcu_b1, fcuW2t, fcu_b2,
        fcvW1t, fcv_b1, fcvW2t, fcv_b2,
        fcW1t, fc_b1, fcW2t, fc_b2,
        euW1t, eu_b1, euW2t, eu_b2,
        EAp, eab);

    x_cur = Hb;
    ea_cur = EAp;
  }

  // outputs: [out (N*128) | ea (in place) | out (N*128)]
  hipMemcpyAsync(out, x_cur, (size_t)N_ * 128 * 4, hipMemcpyDeviceToDevice, stream);
  hipMemcpyAsync(out + (size_t)N_ * 128 + (size_t)E_ * 64, x_cur,
                 (size_t)N_ * 128 * 4, hipMemcpyDeviceToDevice, stream);
}